// Round 3
// baseline (189.421 us; speedup 1.0000x reference)
//
#include <hip/hip_runtime.h>
#include <stdint.h>

#define M_DIM 8192
#define K_DIM 4096
#define N_DIM 4096

using i32x4 = __attribute__((ext_vector_type(4))) int;
using i32x16 = __attribute__((ext_vector_type(16))) int;

typedef const __attribute__((address_space(1))) void g_void;
typedef __attribute__((address_space(3))) void lds_void;

__device__ __forceinline__ void gload_lds16(const void* g, void* l) {
  // async global->LDS, 16B/lane; LDS dest = wave-uniform base + lane*16
  __builtin_amdgcn_global_load_lds((g_void*)g, (lds_void*)l, 16, 0, 0);
}

__device__ __forceinline__ void barrier_raw() {
  asm volatile("" ::: "memory");
  __builtin_amdgcn_s_barrier();
  asm volatile("" ::: "memory");
}

__device__ __forceinline__ int sign4(float4 v) {
  int a = (v.x > 0.f) - (v.x < 0.f);
  int b = (v.y > 0.f) - (v.y < 0.f);
  int c = (v.z > 0.f) - (v.z < 0.f);
  int d = (v.w > 0.f) - (v.w < 0.f);
  return (a & 255) | ((b & 255) << 8) | ((c & 255) << 16) | ((d & 255) << 24);
}

// ---- pack x: fp32 [M][K] -> int8 sign [M][K] ----
__global__ void pack_x_kernel(const float* __restrict__ in,
                              int8_t* __restrict__ out, long n) {
  long i0 = ((long)blockIdx.x * blockDim.x + threadIdx.x) * 16;
  long stride = (long)gridDim.x * blockDim.x * 16;
  for (long i = i0; i < n; i += stride) {
    const float4* p = reinterpret_cast<const float4*>(in + i);
    i32x4 r;
    r.x = sign4(p[0]);
    r.y = sign4(p[1]);
    r.z = sign4(p[2]);
    r.w = sign4(p[3]);
    *reinterpret_cast<i32x4*>(out + i) = r;
  }
}

// ---- pack w: fp32 [K][N] -> int8 sign, TRANSPOSED to [N][K] ----
__global__ void pack_wt_kernel(const float* __restrict__ w,
                               int8_t* __restrict__ wt) {
  __shared__ int8_t tile[64 * 68];
  int n0 = blockIdx.x * 64;
  int k0 = blockIdx.y * 64;
  int t = threadIdx.x;
#pragma unroll
  for (int i = 0; i < 16; ++i) {
    int flat = t + 256 * i;
    int r = flat >> 6;          // k-local
    int c = flat & 63;          // n-local (coalesced)
    float v = w[(long)(k0 + r) * N_DIM + n0 + c];
    tile[c * 68 + r] = (int8_t)((v > 0.f) - (v < 0.f));
  }
  __syncthreads();
#pragma unroll
  for (int i = 0; i < 4; ++i) {
    int flat = t + 256 * i;
    int nn = flat >> 4;
    int kk = (flat & 15) << 2;
    int word = *reinterpret_cast<const int*>(&tile[nn * 68 + kk]);
    *reinterpret_cast<int*>(wt + (long)(n0 + nn) * K_DIM + k0 + kk) = word;
  }
}

// ---- i8 GEMM, 256x256 tile, BK=64, 8 waves (2Mx4N), 4-deep LDS pipeline,
//      mfma_i32_32x32x32_i8, register-fragment ping-pong (reads 1 phase ahead,
//      counted lgkmcnt) ----
// Per wave: 128x64 output = 4x2 fragments of 32x32.
// LDS: 4 buffers x (A 16KB + B 16KB) = 128 KiB.
// Swizzle (both-sides): LDS[row][c] = G[row][c ^ ((row>>1)&3)], rows of 4x16B.
template <int VM, bool ISSUE, bool READ_NEXT>
__device__ __forceinline__ void tile_step(
    int t, const int8_t* __restrict__ Asrc, const int8_t* __restrict__ Bsrc,
    long aOff0, long aOff1, int dstOff, int8_t* lds, int aRd, int bRd,
    int ck0, int ck1, i32x4 (&afA)[4], i32x4 (&bfA)[2], i32x4 (&afB)[4],
    i32x4 (&bfB)[2], i32x16 (&acc)[4][2]) {
  const int8_t* buf = lds + (t & 3) * 32768;
  // ---------- phase 0: read regB (t,q1) || MFMA regA (t,q0) ----------
#pragma unroll
  for (int mi = 0; mi < 4; ++mi)
    afB[mi] = *reinterpret_cast<const i32x4*>(buf + aRd + mi * 2048 + ck1);
#pragma unroll
  for (int ni = 0; ni < 2; ++ni)
    bfB[ni] = *reinterpret_cast<const i32x4*>(buf + bRd + ni * 2048 + ck1);
  if (ISSUE) {
    int kn = (t + 3) * 64;
    int8_t* nbuf = lds + ((t + 3) & 3) * 32768;
    gload_lds16(Asrc + aOff0 + kn, nbuf + dstOff);
    gload_lds16(Asrc + aOff1 + kn, nbuf + 8192 + dstOff);
  }
  asm volatile("s_waitcnt lgkmcnt(6)" ::: "memory");  // regA ready; regB in flight
  __builtin_amdgcn_sched_barrier(0);
  __builtin_amdgcn_s_setprio(1);
#pragma unroll
  for (int mi = 0; mi < 4; ++mi)
#pragma unroll
    for (int ni = 0; ni < 2; ++ni)
      acc[mi][ni] = __builtin_amdgcn_mfma_i32_32x32x32_i8(afA[mi], bfA[ni],
                                                          acc[mi][ni], 0, 0, 0);
  __builtin_amdgcn_s_setprio(0);
  // ---------- phase 1: vm-gate; read regA (t+1,q0); MFMA regB ----------
  if (VM >= 0) {
    if (VM == 6) asm volatile("s_waitcnt vmcnt(6)" ::: "memory");
    else if (VM == 4) asm volatile("s_waitcnt vmcnt(4)" ::: "memory");
    else asm volatile("s_waitcnt vmcnt(0)" ::: "memory");
    barrier_raw();  // all waves' tile-t+1 staging landed
  }
  if (READ_NEXT) {
    const int8_t* nrbuf = lds + ((t + 1) & 3) * 32768;
#pragma unroll
    for (int mi = 0; mi < 4; ++mi)
      afA[mi] = *reinterpret_cast<const i32x4*>(nrbuf + aRd + mi * 2048 + ck0);
#pragma unroll
    for (int ni = 0; ni < 2; ++ni)
      bfA[ni] = *reinterpret_cast<const i32x4*>(nrbuf + bRd + ni * 2048 + ck0);
  }
  if (ISSUE) {
    int kn = (t + 3) * 64;
    int8_t* nbuf = lds + ((t + 3) & 3) * 32768;
    gload_lds16(Bsrc + aOff0 + kn, nbuf + 16384 + dstOff);
    gload_lds16(Bsrc + aOff1 + kn, nbuf + 24576 + dstOff);
  }
  if (READ_NEXT)
    asm volatile("s_waitcnt lgkmcnt(6)" ::: "memory");  // regB ready; regA(t+1) in flight
  else
    asm volatile("s_waitcnt lgkmcnt(0)" ::: "memory");
  __builtin_amdgcn_sched_barrier(0);
  barrier_raw();  // write-gate: every wave done reading buf t
  __builtin_amdgcn_s_setprio(1);
#pragma unroll
  for (int mi = 0; mi < 4; ++mi)
#pragma unroll
    for (int ni = 0; ni < 2; ++ni)
      acc[mi][ni] = __builtin_amdgcn_mfma_i32_32x32x32_i8(afB[mi], bfB[ni],
                                                          acc[mi][ni], 0, 0, 0);
  __builtin_amdgcn_s_setprio(0);
}

__global__ __launch_bounds__(512, 2) void gemm_i8_kernel(
    const int8_t* __restrict__ A, const int8_t* __restrict__ B,
    float* __restrict__ C) {
  __shared__ __align__(16) int8_t lds[4 * 32768];  // 128 KiB

  // XCD-aware bijective swizzle: nwg = 512 = 8 * 64
  int bid = blockIdx.x;
  int wg = (bid & 7) * 64 + (bid >> 3);
  int bm = wg >> 4;  // M/256 = 32
  int bn = wg & 15;  // N/256 = 16

  int tid = threadIdx.x;
  int wid = tid >> 6;
  int lane = tid & 63;
  int wr = wid >> 2;  // 0..1 (M)
  int wc = wid & 3;   // 0..3 (N)

  const int8_t* Asrc = A + (long)bm * 256 * K_DIM;
  const int8_t* Bsrc = B + (long)bn * 256 * K_DIM;

  // staging: dst (linear) row = j*128 + (tid>>2), chunk = tid&3;
  // src chunk = (tid&3) ^ ((row>>1)&3) = (tid&3) ^ ((tid>>3)&3)
  int srcChunk = ((tid & 3) ^ ((tid >> 3) & 3)) << 4;
  long aOff0 = (long)(tid >> 2) * K_DIM + srcChunk;
  long aOff1 = (long)(128 + (tid >> 2)) * K_DIM + srcChunk;
  int dstOff = wid * 1024;  // wave-uniform; HW adds lane*16

  // frag reads: row = (lane&31) within 32-row block; chunk c = q*2 + (lane>>5),
  // swizzled c' = c ^ r3, r3 = ((lane&31)>>1)&3
  int r3 = ((lane & 31) >> 1) & 3;
  int ck0 = (((0 * 2) + (lane >> 5)) ^ r3) << 4;  // q=0 chunk byte-offset
  int ck1 = (((1 * 2) + (lane >> 5)) ^ r3) << 4;  // q=1
  int aRd = (wr * 128 + (lane & 31)) * 64;
  int bRd = 16384 + (wc * 64 + (lane & 31)) * 64;

  i32x4 afA[4], bfA[2], afB[4], bfB[2];
  i32x16 acc[4][2] = {};

  // prologue: stage tiles 0,1,2 (A,B interleaved per tile)
#pragma unroll
  for (int t = 0; t < 3; ++t) {
    int8_t* buf = lds + t * 32768;
    int k0 = t * 64;
    gload_lds16(Asrc + aOff0 + k0, buf + dstOff);
    gload_lds16(Asrc + aOff1 + k0, buf + 8192 + dstOff);
    gload_lds16(Bsrc + aOff0 + k0, buf + 16384 + dstOff);
    gload_lds16(Bsrc + aOff1 + k0, buf + 24576 + dstOff);
  }
  asm volatile("s_waitcnt vmcnt(8)" ::: "memory");  // tile 0 landed; 1,2 in flight
  barrier_raw();
  // preload regA = frags(t=0, q=0)
#pragma unroll
  for (int mi = 0; mi < 4; ++mi)
    afA[mi] = *reinterpret_cast<const i32x4*>(lds + aRd + mi * 2048 + ck0);
#pragma unroll
  for (int ni = 0; ni < 2; ++ni)
    bfA[ni] = *reinterpret_cast<const i32x4*>(lds + bRd + ni * 2048 + ck0);

#pragma unroll 1
  for (int t = 0; t < 61; ++t)
    tile_step<6, true, true>(t, Asrc, Bsrc, aOff0, aOff1, dstOff, lds, aRd, bRd,
                             ck0, ck1, afA, bfA, afB, bfB, acc);
  tile_step<4, false, true>(61, Asrc, Bsrc, aOff0, aOff1, dstOff, lds, aRd, bRd,
                            ck0, ck1, afA, bfA, afB, bfB, acc);
  tile_step<0, false, true>(62, Asrc, Bsrc, aOff0, aOff1, dstOff, lds, aRd, bRd,
                            ck0, ck1, afA, bfA, afB, bfB, acc);
  tile_step<-1, false, false>(63, Asrc, Bsrc, aOff0, aOff1, dstOff, lds, aRd,
                              bRd, ck0, ck1, afA, bfA, afB, bfB, acc);

  // C/D 32x32 layout: col = lane&31, row = (reg&3) + 8*(reg>>2) + 4*(lane>>5)
  long row0 = (long)bm * 256 + wr * 128 + ((lane >> 5) << 2);
  long col0 = (long)bn * 256 + wc * 64 + (lane & 31);
#pragma unroll
  for (int mi = 0; mi < 4; ++mi)
#pragma unroll
    for (int ni = 0; ni < 2; ++ni)
#pragma unroll
      for (int r = 0; r < 16; ++r) {
        long row = row0 + mi * 32 + (r & 3) + ((r >> 2) << 3);
        C[row * N_DIM + col0 + ni * 32] = (float)acc[mi][ni][r];
      }
}

extern "C" void kernel_launch(void* const* d_in, const int* in_sizes, int n_in,
                              void* d_out, int out_size, void* d_ws, size_t ws_size,
                              hipStream_t stream) {
  const float* x = (const float*)d_in[0];
  const float* w = (const float*)d_in[1];
  float* out = (float*)d_out;

  int8_t* xb = (int8_t*)d_ws;                // 32 MB: sign(x) [M][K]
  int8_t* wbt = xb + (size_t)M_DIM * K_DIM;  // 16 MB: sign(w)^T [N][K]

  pack_x_kernel<<<2048, 256, 0, stream>>>(x, xb, (long)M_DIM * K_DIM);
  pack_wt_kernel<<<dim3(N_DIM / 64, K_DIM / 64), 256, 0, stream>>>(w, wbt);
  gemm_i8_kernel<<<512, 512, 0, stream>>>(xb, wbt, out);
}